// Round 9
// baseline (541.074 us; speedup 1.0000x reference)
//
#include <hip/hip_runtime.h>
#include <cstdint>
#include <cstddef>

typedef unsigned short ushort_t;
typedef __bf16 bf16x8 __attribute__((ext_vector_type(8)));
typedef float f32x4 __attribute__((ext_vector_type(4)));

__device__ __forceinline__ float b2f(ushort_t u) {
    return __uint_as_float(((unsigned int)u) << 16);
}
__device__ __forceinline__ ushort_t f2b(float f) {
    __bf16 h = (__bf16)f;  // RNE
    return *(ushort_t*)&h;
}
// bf16 pair unpack from packed uint (little-endian: lo ushort = even channel)
__device__ __forceinline__ float lo16(unsigned int u) { return __uint_as_float(u << 16); }
__device__ __forceinline__ float hi16(unsigned int u) { return __uint_as_float(u & 0xffff0000u); }
__device__ __forceinline__ unsigned int pack2(float a, float b) {
    return ((unsigned int)f2b(b) << 16) | (unsigned int)f2b(a);
}

// stage 8 contiguous elements into LDS as bf16 (overloaded on source type)
__device__ __forceinline__ void stage8(const float* __restrict__ g, ushort_t* s) {
    float4 f0 = *(const float4*)g;
    float4 f1 = *(const float4*)(g + 4);
    union { ushort_t u[8]; uint4 v; } t;
    t.u[0] = f2b(f0.x); t.u[1] = f2b(f0.y); t.u[2] = f2b(f0.z); t.u[3] = f2b(f0.w);
    t.u[4] = f2b(f1.x); t.u[5] = f2b(f1.y); t.u[6] = f2b(f1.z); t.u[7] = f2b(f1.w);
    *(uint4*)s = t.v;
}
__device__ __forceinline__ void stage8(const ushort_t* __restrict__ g, ushort_t* s) {
    *(float4*)s = *(const float4*)g;  // already bf16: raw 16B copy
}

// ---------------- all 4 weight transposes + deg zeroing in one launch ----------------
__device__ __forceinline__ void tr_seg(int id, const float* __restrict__ W,
                                       ushort_t* __restrict__ WT, int K, int N2) {
    int n = id / K, k = id - n * K;
    WT[id] = f2b(W[k * N2 + n]);
}
__global__ __launch_bounds__(256) void transpose_all_kernel(const float* __restrict__ W1,
                                                            const float* __restrict__ W2,
                                                            const float* __restrict__ W3,
                                                            const float* __restrict__ Wfc,
                                                            ushort_t* __restrict__ W1T,
                                                            ushort_t* __restrict__ W2T,
                                                            ushort_t* __restrict__ W3T,
                                                            ushort_t* __restrict__ WfcT,
                                                            int* __restrict__ deg, int n) {
    int id = blockIdx.x * 256 + threadIdx.x;
    if (id < n) deg[id] = 0;  // fused memset (runs before degree_kernel in-stream)
    if (id < 32768) { tr_seg(id, W1, W1T, 128, 256); return; }
    id -= 32768;
    if (id < 65536) { tr_seg(id, W2, W2T, 256, 256); return; }
    id -= 65536;
    if (id < 16384) { tr_seg(id, W3, W3T, 256, 64); return; }
    id -= 16384;
    if (id < 32768) { tr_seg(id, Wfc, WfcT, 64, 512); return; }
}

// ---------------- CSR build ----------------
__global__ __launch_bounds__(256) void degree_kernel(const int* __restrict__ ei_dst,
                                                     int* __restrict__ deg, int E, int Etot) {
    int e = blockIdx.x * 256 + threadIdx.x;
    if (e >= Etot) return;
    int d = (e < E) ? ei_dst[e] : (e - E);
    atomicAdd(&deg[d], 1);
}

__global__ __launch_bounds__(256) void partial_sum_kernel(const int* __restrict__ deg,
                                                          int* __restrict__ bsum, int n) {
    __shared__ int ws[4];
    int t = threadIdx.x;
    int i = blockIdx.x * 256 + t;
    int v = (i < n) ? deg[i] : 0;
#pragma unroll
    for (int off = 32; off; off >>= 1) v += __shfl_xor(v, off, 64);
    if ((t & 63) == 0) ws[t >> 6] = v;
    __syncthreads();
    if (t == 0) bsum[blockIdx.x] = ws[0] + ws[1] + ws[2] + ws[3];
}

__global__ __launch_bounds__(256) void scan_bsum_kernel(const int* __restrict__ bsum,
                                                        int* __restrict__ boff,
                                                        int* __restrict__ rowoff,
                                                        int nblk, int n) {
    __shared__ int sm[256];
    int t = threadIdx.x;
    int v = (t < nblk) ? bsum[t] : 0;
    sm[t] = v;
    __syncthreads();
#pragma unroll
    for (int off = 1; off < 256; off <<= 1) {
        int u = (t >= off) ? sm[t - off] : 0;
        __syncthreads();
        sm[t] += u;
        __syncthreads();
    }
    if (t < nblk) boff[t] = sm[t] - v;
    if (t == 255) rowoff[n] = sm[255];
}

// per-block inclusive scan + block offset -> exclusive rowoff[i]; also cursor[i]=rowoff[i]
__global__ __launch_bounds__(256) void block_scan_kernel(const int* __restrict__ deg,
                                                         const int* __restrict__ boff,
                                                         int* __restrict__ rowoff,
                                                         int* __restrict__ cursor, int n) {
    __shared__ int sm[256];
    int t = threadIdx.x;
    int i = blockIdx.x * 256 + t;
    int v = (i < n) ? deg[i] : 0;
    sm[t] = v;
    __syncthreads();
#pragma unroll
    for (int off = 1; off < 256; off <<= 1) {
        int u = (t >= off) ? sm[t - off] : 0;
        __syncthreads();
        sm[t] += u;
        __syncthreads();
    }
    if (i < n) {
        int r = boff[blockIdx.x] + sm[t] - v;
        rowoff[i] = r;
        cursor[i] = r;
    }
}

__global__ __launch_bounds__(256) void scatter_kernel(const int* __restrict__ ei_src,
                                                      const int* __restrict__ ei_dst,
                                                      int* __restrict__ cursor,
                                                      int* __restrict__ ssrc, int E, int Etot) {
    int e = blockIdx.x * 256 + threadIdx.x;
    if (e >= Etot) return;
    int s, d;
    if (e < E) { s = ei_src[e]; d = ei_dst[e]; } else { s = d = e - E; }
    int pos = atomicAdd(&cursor[d], 1);
    ssrc[pos] = s;
}

// ---------------- 128x128 MFMA GEMM, optional fused attention epilogue ----------------
// 256 thr = 4 waves in 2x2; wave (wr,wc) owns 64x64 quadrant; 4x4 16x16-frag accum.
// EPI: 1 = fp32 bias+relu out, 2 = bf16 out + fused attn (wave holds all 64 ch of one head).
// SMAJ: bf16 output in slice-major layout xs[col>>5][row][col&31] for XCD-sliced aggregation.
template <typename TA, int EPI, bool SMAJ>
__global__ __launch_bounds__(256) void gemm128_mfma(const TA* __restrict__ A,
                                                    const ushort_t* __restrict__ WT,
                                                    float* __restrict__ C,
                                                    ushort_t* __restrict__ Cb,
                                                    const float* __restrict__ bias,
                                                    const float* __restrict__ a_src,
                                                    const float* __restrict__ a_dst,
                                                    float* __restrict__ as_n,
                                                    float* __restrict__ ad_n,
                                                    int M, int K, int N2) {
    __shared__ ushort_t sA[128 * 32];  // 8 KB
    __shared__ ushort_t sB[128 * 32];  // 8 KB
    const int tid = threadIdx.x;
    const int wv = tid >> 6, lane = tid & 63;
    const int wr = wv >> 1, wc = wv & 1;
    const int quad = lane >> 4, l16 = lane & 15;
    const int bm = blockIdx.x * 128, bn = blockIdx.y * 128;
    const int sr0 = tid >> 2, sc = (tid & 3) * 8;
    const int sr1 = sr0 + 64;
    f32x4 acc[4][4] = {};

    int ga0 = bm + sr0; ga0 = ga0 < M ? ga0 : M - 1;  // clamp tail (dup read; masked store)
    int ga1 = bm + sr1; ga1 = ga1 < M ? ga1 : M - 1;
    const TA* pa0 = A + (size_t)ga0 * K + sc;
    const TA* pa1 = A + (size_t)ga1 * K + sc;
    const ushort_t* pb0 = WT + (size_t)(bn + sr0) * K + sc;
    const ushort_t* pb1 = WT + (size_t)(bn + sr1) * K + sc;

    for (int k0 = 0; k0 < K; k0 += 32) {
        stage8(pa0 + k0, sA + sr0 * 32 + sc);
        stage8(pa1 + k0, sA + sr1 * 32 + sc);
        stage8(pb0 + k0, sB + sr0 * 32 + sc);
        stage8(pb1 + k0, sB + sr1 * 32 + sc);
        __syncthreads();

        bf16x8 af[4], bfr[4];
#pragma unroll
        for (int m = 0; m < 4; m++)
            af[m] = *(const bf16x8*)(sA + (wr * 64 + m * 16 + l16) * 32 + quad * 8);
#pragma unroll
        for (int n = 0; n < 4; n++)
            bfr[n] = *(const bf16x8*)(sB + (wc * 64 + n * 16 + l16) * 32 + quad * 8);
#pragma unroll
        for (int m = 0; m < 4; m++)
#pragma unroll
            for (int n = 0; n < 4; n++)
                acc[m][n] = __builtin_amdgcn_mfma_f32_16x16x32_bf16(af[m], bfr[n], acc[m][n], 0, 0, 0);
        __syncthreads();
    }

#pragma unroll
    for (int n = 0; n < 4; n++) {
        int col = bn + wc * 64 + n * 16 + l16;
        float bv = (EPI == 1) ? bias[col] : 0.f;
#pragma unroll
        for (int m = 0; m < 4; m++) {
#pragma unroll
            for (int r = 0; r < 4; r++) {
                int row = bm + wr * 64 + m * 16 + quad * 4 + r;
                if (row < M) {
                    float v = acc[m][n][r];
                    if (EPI == 1) {
                        v += bv;
                        v = v > 0.f ? v : 0.f;
                        C[(size_t)row * N2 + col] = v;
                    } else if (SMAJ) {
                        Cb[((size_t)(col >> 5) * M + row) * 32 + (col & 31)] = f2b(v);
                    } else {
                        Cb[(size_t)row * N2 + col] = f2b(v);
                    }
                }
            }
        }
    }

    if (EPI == 2) {
        const int head = blockIdx.y * 2 + wc;
        float asv[4], adv[4];
#pragma unroll
        for (int n = 0; n < 4; n++) {
            asv[n] = a_src[head * 64 + n * 16 + l16];
            adv[n] = a_dst[head * 64 + n * 16 + l16];
        }
        float ps[4][4] = {}, pd[4][4] = {};
#pragma unroll
        for (int n = 0; n < 4; n++)
#pragma unroll
            for (int m = 0; m < 4; m++)
#pragma unroll
                for (int r = 0; r < 4; r++) {
                    ps[m][r] += acc[m][n][r] * asv[n];
                    pd[m][r] += acc[m][n][r] * adv[n];
                }
#pragma unroll
        for (int off = 1; off < 16; off <<= 1)
#pragma unroll
            for (int m = 0; m < 4; m++)
#pragma unroll
                for (int r = 0; r < 4; r++) {
                    ps[m][r] += __shfl_xor(ps[m][r], off, 64);
                    pd[m][r] += __shfl_xor(pd[m][r], off, 64);
                }
        if (l16 == 0) {
#pragma unroll
            for (int m = 0; m < 4; m++)
#pragma unroll
                for (int r = 0; r < 4; r++) {
                    int row = bm + wr * 64 + m * 16 + quad * 4 + r;
                    if (row < M) {
                        as_n[row * 4 + head] = ps[m][r];
                        ad_n[row * 4 + head] = pd[m][r];
                    }
                }
        }
    }
}

// ---------------- 64x64 MFMA GEMM with fused attn (layer-3: N2=64, 1 head) ----------------
__global__ __launch_bounds__(256) void gemm64_mfma(const ushort_t* __restrict__ A,
                                                   const ushort_t* __restrict__ WT,
                                                   ushort_t* __restrict__ Cb,
                                                   const float* __restrict__ a_src,
                                                   const float* __restrict__ a_dst,
                                                   float* __restrict__ as_n,
                                                   float* __restrict__ ad_n,
                                                   int M, int K, int N2) {
    __shared__ ushort_t sA[64 * 32];  // 4 KB
    __shared__ ushort_t sB[64 * 32];  // 4 KB
    const int tid = threadIdx.x;
    const int wv = tid >> 6, lane = tid & 63;
    const int quad = lane >> 4, l16 = lane & 15;
    const int bm = blockIdx.x * 64;
    const int srow = tid >> 2, skof = (tid & 3) * 8;
    f32x4 acc[4] = {};

    int gm = bm + srow;
    gm = gm < M ? gm : M - 1;
    const ushort_t* pa = A + (size_t)gm * K + skof;
    const ushort_t* pb = WT + (size_t)srow * K + skof;

    for (int k0 = 0; k0 < K; k0 += 32) {
        *(float4*)(sA + srow * 32 + skof) = *(const float4*)(pa + k0);
        *(float4*)(sB + srow * 32 + skof) = *(const float4*)(pb + k0);
        __syncthreads();

        bf16x8 af = *(const bf16x8*)(sA + (wv * 16 + l16) * 32 + quad * 8);
#pragma unroll
        for (int j = 0; j < 4; j++) {
            bf16x8 bf = *(const bf16x8*)(sB + (j * 16 + l16) * 32 + quad * 8);
            acc[j] = __builtin_amdgcn_mfma_f32_16x16x32_bf16(af, bf, acc[j], 0, 0, 0);
        }
        __syncthreads();
    }

#pragma unroll
    for (int j = 0; j < 4; j++) {
        int col = j * 16 + l16;
#pragma unroll
        for (int r = 0; r < 4; r++) {
            int row = bm + wv * 16 + quad * 4 + r;
            if (row < M) Cb[(size_t)row * N2 + col] = f2b(acc[j][r]);
        }
    }

    // fused attn: the wave's 4 j-frags x 16 lanes span all 64 cols (single head)
    float asv[4], adv[4];
#pragma unroll
    for (int j = 0; j < 4; j++) {
        asv[j] = a_src[j * 16 + l16];
        adv[j] = a_dst[j * 16 + l16];
    }
    float ps[4] = {}, pd[4] = {};
#pragma unroll
    for (int j = 0; j < 4; j++)
#pragma unroll
        for (int r = 0; r < 4; r++) {
            ps[r] += acc[j][r] * asv[j];
            pd[r] += acc[j][r] * adv[j];
        }
#pragma unroll
    for (int off = 1; off < 16; off <<= 1)
#pragma unroll
        for (int r = 0; r < 4; r++) {
            ps[r] += __shfl_xor(ps[r], off, 64);
            pd[r] += __shfl_xor(pd[r], off, 64);
        }
    if (l16 == 0) {
#pragma unroll
        for (int r = 0; r < 4; r++) {
            int row = bm + wv * 16 + quad * 4 + r;
            if (row < M) {
                as_n[row] = ps[r];
                ad_n[row] = pd[r];
            }
        }
    }
}

// ---------------- XCD-sliced softmax aggregation (CH=256) ----------------
// xl stored slice-major: xs[slice][N][32ch]; slice = blockIdx.x & 7 -> lands on one XCD
// (round-robin dispatch), so each XCD's gather working set is 3.2 MB -> L2-resident.
// Per wave: 2 dsts x (8 edge-slots x 4 ch-lanes). Cross-slot shfl reduce at the end.
// Correctness does NOT depend on the XCD mapping; only locality does.
__global__ __launch_bounds__(256) void aggregate256_slice_kernel(
    const ushort_t* __restrict__ xs, const float* __restrict__ as_n,
    const float* __restrict__ ad_n, const int* __restrict__ rowoff,
    const int* __restrict__ ssrc, const float* __restrict__ bias,
    ushort_t* __restrict__ hout, int N) {
    const int bid = blockIdx.x;
    const int slice = bid & 7;
    const int db = bid >> 3;
    const int tid = threadIdx.x;
    const int wv = tid >> 6, lane = tid & 63;
    const int half = lane >> 5, l32 = lane & 31;
    const int slot = l32 >> 2, sub = l32 & 3;
    const int dd = db * 8 + wv * 2 + half;
    if (dd >= N) return;
    const int h = slice >> 1;
    const int r0 = rowoff[dd], r1 = rowoff[dd + 1];
    const float adv = ad_n[dd * 4 + h];
    const uint4* xv = (const uint4*)xs;          // (slice*N + s)*4 + sub
    const size_t sbase = (size_t)slice * N;
    float a0 = 0, a1 = 0, a2 = 0, a3 = 0, a4 = 0, a5 = 0, a6 = 0, a7 = 0, den = 0;
    for (int i = r0 + slot; i < r1; i += 8) {
        int s = ssrc[i];
        float lg = as_n[s * 4 + h] + adv;
        lg = lg > 0.f ? lg : 0.2f * lg;
        float p = __expf(lg);
        uint4 u = xv[(sbase + s) * 4 + sub];
        den += p;
        a0 += p * lo16(u.x); a1 += p * hi16(u.x);
        a2 += p * lo16(u.y); a3 += p * hi16(u.y);
        a4 += p * lo16(u.z); a5 += p * hi16(u.z);
        a6 += p * lo16(u.w); a7 += p * hi16(u.w);
    }
    // reduce across the 8 edge-slots (strides 4,8,16 stay within the 32-lane dst half)
#pragma unroll
    for (int off = 4; off < 32; off <<= 1) {
        a0 += __shfl_xor(a0, off, 64); a1 += __shfl_xor(a1, off, 64);
        a2 += __shfl_xor(a2, off, 64); a3 += __shfl_xor(a3, off, 64);
        a4 += __shfl_xor(a4, off, 64); a5 += __shfl_xor(a5, off, 64);
        a6 += __shfl_xor(a6, off, 64); a7 += __shfl_xor(a7, off, 64);
        den += __shfl_xor(den, off, 64);
    }
    if (slot == 0) {
        float di = 1.f / (den + 1e-16f);
        const float4* bp = (const float4*)(bias + slice * 32 + sub * 8);
        float4 b0 = bp[0], b1 = bp[1];
        float v0 = a0 * di + b0.x, v1 = a1 * di + b0.y;
        float v2 = a2 * di + b0.z, v3 = a3 * di + b0.w;
        float v4 = a4 * di + b1.x, v5 = a5 * di + b1.y;
        float v6 = a6 * di + b1.z, v7 = a7 * di + b1.w;
        v0 = v0 > 0.f ? v0 : 0.f; v1 = v1 > 0.f ? v1 : 0.f;
        v2 = v2 > 0.f ? v2 : 0.f; v3 = v3 > 0.f ? v3 : 0.f;
        v4 = v4 > 0.f ? v4 : 0.f; v5 = v5 > 0.f ? v5 : 0.f;
        v6 = v6 > 0.f ? v6 : 0.f; v7 = v7 > 0.f ? v7 : 0.f;
        uint4 o;
        o.x = pack2(v0, v1); o.y = pack2(v2, v3);
        o.z = pack2(v4, v5); o.w = pack2(v6, v7);
        ((uint4*)hout)[(size_t)dd * 32 + slice * 4 + sub] = o;  // normal [N][256] out
    }
}

// ---------------- per-dst softmax-weighted aggregation (CH=64, layer 3) ----------------
__global__ __launch_bounds__(256) void aggregate64_kernel(const ushort_t* __restrict__ xl,
                                                          const float* __restrict__ as_n,
                                                          const float* __restrict__ ad_n,
                                                          const int* __restrict__ rowoff,
                                                          const int* __restrict__ ssrc,
                                                          const float* __restrict__ bias,
                                                          ushort_t* __restrict__ hout, int N) {
    const int tid = threadIdx.x;
    const int wv = tid >> 6, lane = tid & 63;
    const uint4* xv = (const uint4*)xl;
    const int grp = lane >> 3, l8 = lane & 7;
    const int dd = blockIdx.x * 32 + wv * 8 + grp;
    if (dd >= N) return;
    const int r0 = rowoff[dd], r1 = rowoff[dd + 1];
    const float adv = ad_n[dd];
    float a0 = 0, a1 = 0, a2 = 0, a3 = 0, a4 = 0, a5 = 0, a6 = 0, a7 = 0, den = 0;
    for (int i = r0; i < r1; i += 8) {
        int s[8];
        float g[8];
        uint4 u[8];
#pragma unroll
        for (int j = 0; j < 8; j++) {
            int t = i + j;
            s[j] = ssrc[t < r1 ? t : r0];
        }
#pragma unroll
        for (int j = 0; j < 8; j++) g[j] = as_n[s[j]];
#pragma unroll
        for (int j = 0; j < 8; j++) u[j] = xv[(size_t)s[j] * 8 + l8];
#pragma unroll
        for (int j = 0; j < 8; j++) {
            float lg = g[j] + adv;
            lg = lg > 0.f ? lg : 0.2f * lg;
            float p = (i + j < r1) ? __expf(lg) : 0.f;
            den += p;
            a0 += p * lo16(u[j].x); a1 += p * hi16(u[j].x);
            a2 += p * lo16(u[j].y); a3 += p * hi16(u[j].y);
            a4 += p * lo16(u[j].z); a5 += p * hi16(u[j].z);
            a6 += p * lo16(u[j].w); a7 += p * hi16(u[j].w);
        }
    }
    float di = 1.f / (den + 1e-16f);
    float4 b0 = ((const float4*)bias)[l8 * 2];
    float4 b1 = ((const float4*)bias)[l8 * 2 + 1];
    float v0 = a0 * di + b0.x, v1 = a1 * di + b0.y;
    float v2 = a2 * di + b0.z, v3 = a3 * di + b0.w;
    float v4 = a4 * di + b1.x, v5 = a5 * di + b1.y;
    float v6 = a6 * di + b1.z, v7 = a7 * di + b1.w;
    v0 = v0 > 0.f ? v0 : 0.f; v1 = v1 > 0.f ? v1 : 0.f;
    v2 = v2 > 0.f ? v2 : 0.f; v3 = v3 > 0.f ? v3 : 0.f;
    v4 = v4 > 0.f ? v4 : 0.f; v5 = v5 > 0.f ? v5 : 0.f;
    v6 = v6 > 0.f ? v6 : 0.f; v7 = v7 > 0.f ? v7 : 0.f;
    uint4 o;
    o.x = pack2(v0, v1); o.y = pack2(v2, v3);
    o.z = pack2(v4, v5); o.w = pack2(v6, v7);
    ((uint4*)hout)[(size_t)dd * 8 + l8] = o;
}

extern "C" void kernel_launch(void* const* d_in, const int* in_sizes, int n_in,
                              void* d_out, int out_size, void* d_ws, size_t ws_size,
                              hipStream_t stream) {
    const int N = in_sizes[0] / 128;  // 50000
    const int E = in_sizes[1] / 2;    // 800000
    const int Etot = E + N;

    const float* x = (const float*)d_in[0];  // fp32 input
    const int* ei = (const int*)d_in[1];
    const int* ei_src = ei;
    const int* ei_dst = ei + E;
    float* out = (float*)d_out;  // fp32 output

    const float* as1 = (const float*)d_in[3];
    const float* ad1 = (const float*)d_in[4];
    const float* b1  = (const float*)d_in[5];
    const float* as2 = (const float*)d_in[7];
    const float* ad2 = (const float*)d_in[8];
    const float* b2  = (const float*)d_in[9];
    const float* as3 = (const float*)d_in[11];
    const float* ad3 = (const float*)d_in[12];
    const float* b3  = (const float*)d_in[13];
    const float* bfc = (const float*)d_in[15];

    // ---- workspace layout (bf16 activations) ----
    ushort_t* bufX = (ushort_t*)d_ws;            // [N][256] bf16 (xl; slice-major for L1/L2)
    ushort_t* bufH = bufX + (size_t)N * 256;     // [N][256] bf16 (agg out)
    ushort_t* W1T  = bufH + (size_t)N * 256;     // 256x128 bf16
    ushort_t* W2T  = W1T + 32768;                // 256x256
    ushort_t* W3T  = W2T + 65536;                // 64x256
    ushort_t* WfcT = W3T + 16384;                // 512x64
    float* asn = (float*)(WfcT + 32768);         // N*4
    float* adn = asn + (size_t)N * 4;            // N*4
    int* deg    = (int*)(adn + (size_t)N * 4);   // N
    int* rowoff = deg + N;                       // N+1
    int* cursor = rowoff + N + 1;                // N
    int* ssrc   = cursor + N;                    // Etot
    int* bsum   = ssrc + Etot;                   // <=256
    int* boff   = bsum + 256;                    // <=256

    // weight transposes + deg zeroing in one launch
    transpose_all_kernel<<<576, 256, 0, stream>>>((const float*)d_in[2], (const float*)d_in[6],
                                                  (const float*)d_in[10], (const float*)d_in[14],
                                                  W1T, W2T, W3T, WfcT, deg, N);

    // CSR build
    int eb = (Etot + 255) / 256;
    degree_kernel<<<eb, 256, 0, stream>>>(ei_dst, deg, E, Etot);
    const int NBLK = (N + 255) / 256;  // 196 (<= 256)
    partial_sum_kernel<<<NBLK, 256, 0, stream>>>(deg, bsum, N);
    scan_bsum_kernel<<<1, 256, 0, stream>>>(bsum, boff, rowoff, NBLK, N);
    block_scan_kernel<<<NBLK, 256, 0, stream>>>(deg, boff, rowoff, cursor, N);
    scatter_kernel<<<eb, 256, 0, stream>>>(ei_src, ei_dst, cursor, ssrc, E, Etot);

    const int MB128 = (N + 127) / 128;  // 391
    const int MB64 = (N + 63) / 64;     // 782
    const int nbS = ((N + 7) / 8) * 8;  // 50000 blocks (8 slices)
    int nb32 = (N + 31) / 32;

    // layer 1: x(fp32) @ W1 -> bufX(slice-major bf16) + fused attn; sliced aggregate -> bufH
    gemm128_mfma<float, 2, true><<<dim3(MB128, 2), 256, 0, stream>>>(
        x, W1T, nullptr, bufX, nullptr, as1, ad1, asn, adn, N, 128, 256);
    aggregate256_slice_kernel<<<nbS, 256, 0, stream>>>(bufX, asn, adn, rowoff, ssrc, b1, bufH, N);

    // layer 2
    gemm128_mfma<ushort_t, 2, true><<<dim3(MB128, 2), 256, 0, stream>>>(
        bufH, W2T, nullptr, bufX, nullptr, as2, ad2, asn, adn, N, 256, 256);
    aggregate256_slice_kernel<<<nbS, 256, 0, stream>>>(bufX, asn, adn, rowoff, ssrc, b2, bufH, N);

    // layer 3 (H=1, C=64) + fused attn (normal layout)
    gemm64_mfma<<<dim3(MB64, 1), 256, 0, stream>>>(bufH, W3T, bufX, as3, ad3, asn, adn, N, 256, 64);
    aggregate64_kernel<<<nb32, 256, 0, stream>>>(bufX, asn, adn, rowoff, ssrc, b3, bufH, N);

    // final fc: relu(bufH[N,64] @ Wfc + bfc) -> fp32 out
    gemm128_mfma<ushort_t, 1, false><<<dim3(MB128, 4), 256, 0, stream>>>(
        bufH, WfcT, out, nullptr, bfc, nullptr, nullptr, nullptr, nullptr, N, 64, 512);
}

// Round 10
// 516.384 us; speedup vs baseline: 1.0478x; 1.0478x over previous
//
#include <hip/hip_runtime.h>
#include <cstdint>
#include <cstddef>

typedef unsigned short ushort_t;
typedef __bf16 bf16x8 __attribute__((ext_vector_type(8)));
typedef float f32x4 __attribute__((ext_vector_type(4)));

__device__ __forceinline__ float b2f(ushort_t u) {
    return __uint_as_float(((unsigned int)u) << 16);
}
__device__ __forceinline__ ushort_t f2b(float f) {
    __bf16 h = (__bf16)f;  // RNE
    return *(ushort_t*)&h;
}
// bf16 pair unpack from packed uint (little-endian: lo ushort = even channel)
__device__ __forceinline__ float lo16(unsigned int u) { return __uint_as_float(u << 16); }
__device__ __forceinline__ float hi16(unsigned int u) { return __uint_as_float(u & 0xffff0000u); }
__device__ __forceinline__ unsigned int pack2(float a, float b) {
    return ((unsigned int)f2b(b) << 16) | (unsigned int)f2b(a);
}

// stage 8 contiguous elements into LDS as bf16 (overloaded on source type)
__device__ __forceinline__ void stage8(const float* __restrict__ g, ushort_t* s) {
    float4 f0 = *(const float4*)g;
    float4 f1 = *(const float4*)(g + 4);
    union { ushort_t u[8]; uint4 v; } t;
    t.u[0] = f2b(f0.x); t.u[1] = f2b(f0.y); t.u[2] = f2b(f0.z); t.u[3] = f2b(f0.w);
    t.u[4] = f2b(f1.x); t.u[5] = f2b(f1.y); t.u[6] = f2b(f1.z); t.u[7] = f2b(f1.w);
    *(uint4*)s = t.v;
}
__device__ __forceinline__ void stage8(const ushort_t* __restrict__ g, ushort_t* s) {
    *(float4*)s = *(const float4*)g;  // already bf16: raw 16B copy
}

// ---------------- all 4 weight transposes + deg zeroing in one launch ----------------
__device__ __forceinline__ void tr_seg(int id, const float* __restrict__ W,
                                       ushort_t* __restrict__ WT, int K, int N2) {
    int n = id / K, k = id - n * K;
    WT[id] = f2b(W[k * N2 + n]);
}
__global__ __launch_bounds__(256) void transpose_all_kernel(const float* __restrict__ W1,
                                                            const float* __restrict__ W2,
                                                            const float* __restrict__ W3,
                                                            const float* __restrict__ Wfc,
                                                            ushort_t* __restrict__ W1T,
                                                            ushort_t* __restrict__ W2T,
                                                            ushort_t* __restrict__ W3T,
                                                            ushort_t* __restrict__ WfcT,
                                                            int* __restrict__ deg, int n) {
    int id = blockIdx.x * 256 + threadIdx.x;
    if (id < n) deg[id] = 0;  // fused memset (runs before degree_kernel in-stream)
    if (id < 32768) { tr_seg(id, W1, W1T, 128, 256); return; }
    id -= 32768;
    if (id < 65536) { tr_seg(id, W2, W2T, 256, 256); return; }
    id -= 65536;
    if (id < 16384) { tr_seg(id, W3, W3T, 256, 64); return; }
    id -= 16384;
    if (id < 32768) { tr_seg(id, Wfc, WfcT, 64, 512); return; }
}

// ---------------- CSR build ----------------
__global__ __launch_bounds__(256) void degree_kernel(const int* __restrict__ ei_dst,
                                                     int* __restrict__ deg, int E, int Etot) {
    int e = blockIdx.x * 256 + threadIdx.x;
    if (e >= Etot) return;
    int d = (e < E) ? ei_dst[e] : (e - E);
    atomicAdd(&deg[d], 1);
}

__global__ __launch_bounds__(256) void partial_sum_kernel(const int* __restrict__ deg,
                                                          int* __restrict__ bsum, int n) {
    __shared__ int ws[4];
    int t = threadIdx.x;
    int i = blockIdx.x * 256 + t;
    int v = (i < n) ? deg[i] : 0;
#pragma unroll
    for (int off = 32; off; off >>= 1) v += __shfl_xor(v, off, 64);
    if ((t & 63) == 0) ws[t >> 6] = v;
    __syncthreads();
    if (t == 0) bsum[blockIdx.x] = ws[0] + ws[1] + ws[2] + ws[3];
}

__global__ __launch_bounds__(256) void scan_bsum_kernel(const int* __restrict__ bsum,
                                                        int* __restrict__ boff,
                                                        int* __restrict__ rowoff,
                                                        int nblk, int n) {
    __shared__ int sm[256];
    int t = threadIdx.x;
    int v = (t < nblk) ? bsum[t] : 0;
    sm[t] = v;
    __syncthreads();
#pragma unroll
    for (int off = 1; off < 256; off <<= 1) {
        int u = (t >= off) ? sm[t - off] : 0;
        __syncthreads();
        sm[t] += u;
        __syncthreads();
    }
    if (t < nblk) boff[t] = sm[t] - v;
    if (t == 255) rowoff[n] = sm[255];
}

// per-block inclusive scan + block offset -> exclusive rowoff[i]; also cursor[i]=rowoff[i]
__global__ __launch_bounds__(256) void block_scan_kernel(const int* __restrict__ deg,
                                                         const int* __restrict__ boff,
                                                         int* __restrict__ rowoff,
                                                         int* __restrict__ cursor, int n) {
    __shared__ int sm[256];
    int t = threadIdx.x;
    int i = blockIdx.x * 256 + t;
    int v = (i < n) ? deg[i] : 0;
    sm[t] = v;
    __syncthreads();
#pragma unroll
    for (int off = 1; off < 256; off <<= 1) {
        int u = (t >= off) ? sm[t - off] : 0;
        __syncthreads();
        sm[t] += u;
        __syncthreads();
    }
    if (i < n) {
        int r = boff[blockIdx.x] + sm[t] - v;
        rowoff[i] = r;
        cursor[i] = r;
    }
}

__global__ __launch_bounds__(256) void scatter_kernel(const int* __restrict__ ei_src,
                                                      const int* __restrict__ ei_dst,
                                                      int* __restrict__ cursor,
                                                      int* __restrict__ ssrc, int E, int Etot) {
    int e = blockIdx.x * 256 + threadIdx.x;
    if (e >= Etot) return;
    int s, d;
    if (e < E) { s = ei_src[e]; d = ei_dst[e]; } else { s = d = e - E; }
    int pos = atomicAdd(&cursor[d], 1);
    ssrc[pos] = s;
}

// ---------------- 128x128 MFMA GEMM, optional fused attention epilogue ----------------
// EPI: 1 = fp32 bias+relu out, 2 = bf16 out + fused attn (wave holds all 64 ch of one head).
// SMAJ: bf16 output in slice-major layout xs[col>>5][row][col&31] for XCD-sliced aggregation.
template <typename TA, int EPI, bool SMAJ>
__global__ __launch_bounds__(256) void gemm128_mfma(const TA* __restrict__ A,
                                                    const ushort_t* __restrict__ WT,
                                                    float* __restrict__ C,
                                                    ushort_t* __restrict__ Cb,
                                                    const float* __restrict__ bias,
                                                    const float* __restrict__ a_src,
                                                    const float* __restrict__ a_dst,
                                                    float* __restrict__ as_n,
                                                    float* __restrict__ ad_n,
                                                    int M, int K, int N2) {
    __shared__ ushort_t sA[128 * 32];  // 8 KB
    __shared__ ushort_t sB[128 * 32];  // 8 KB
    const int tid = threadIdx.x;
    const int wv = tid >> 6, lane = tid & 63;
    const int wr = wv >> 1, wc = wv & 1;
    const int quad = lane >> 4, l16 = lane & 15;
    const int bm = blockIdx.x * 128, bn = blockIdx.y * 128;
    const int sr0 = tid >> 2, sc = (tid & 3) * 8;
    const int sr1 = sr0 + 64;
    f32x4 acc[4][4] = {};

    int ga0 = bm + sr0; ga0 = ga0 < M ? ga0 : M - 1;  // clamp tail (dup read; masked store)
    int ga1 = bm + sr1; ga1 = ga1 < M ? ga1 : M - 1;
    const TA* pa0 = A + (size_t)ga0 * K + sc;
    const TA* pa1 = A + (size_t)ga1 * K + sc;
    const ushort_t* pb0 = WT + (size_t)(bn + sr0) * K + sc;
    const ushort_t* pb1 = WT + (size_t)(bn + sr1) * K + sc;

    for (int k0 = 0; k0 < K; k0 += 32) {
        stage8(pa0 + k0, sA + sr0 * 32 + sc);
        stage8(pa1 + k0, sA + sr1 * 32 + sc);
        stage8(pb0 + k0, sB + sr0 * 32 + sc);
        stage8(pb1 + k0, sB + sr1 * 32 + sc);
        __syncthreads();

        bf16x8 af[4], bfr[4];
#pragma unroll
        for (int m = 0; m < 4; m++)
            af[m] = *(const bf16x8*)(sA + (wr * 64 + m * 16 + l16) * 32 + quad * 8);
#pragma unroll
        for (int n = 0; n < 4; n++)
            bfr[n] = *(const bf16x8*)(sB + (wc * 64 + n * 16 + l16) * 32 + quad * 8);
#pragma unroll
        for (int m = 0; m < 4; m++)
#pragma unroll
            for (int n = 0; n < 4; n++)
                acc[m][n] = __builtin_amdgcn_mfma_f32_16x16x32_bf16(af[m], bfr[n], acc[m][n], 0, 0, 0);
        __syncthreads();
    }

#pragma unroll
    for (int n = 0; n < 4; n++) {
        int col = bn + wc * 64 + n * 16 + l16;
        float bv = (EPI == 1) ? bias[col] : 0.f;
#pragma unroll
        for (int m = 0; m < 4; m++) {
#pragma unroll
            for (int r = 0; r < 4; r++) {
                int row = bm + wr * 64 + m * 16 + quad * 4 + r;
                if (row < M) {
                    float v = acc[m][n][r];
                    if (EPI == 1) {
                        v += bv;
                        v = v > 0.f ? v : 0.f;
                        C[(size_t)row * N2 + col] = v;
                    } else if (SMAJ) {
                        Cb[((size_t)(col >> 5) * M + row) * 32 + (col & 31)] = f2b(v);
                    } else {
                        Cb[(size_t)row * N2 + col] = f2b(v);
                    }
                }
            }
        }
    }

    if (EPI == 2) {
        const int head = blockIdx.y * 2 + wc;
        float asv[4], adv[4];
#pragma unroll
        for (int n = 0; n < 4; n++) {
            asv[n] = a_src[head * 64 + n * 16 + l16];
            adv[n] = a_dst[head * 64 + n * 16 + l16];
        }
        float ps[4][4] = {}, pd[4][4] = {};
#pragma unroll
        for (int n = 0; n < 4; n++)
#pragma unroll
            for (int m = 0; m < 4; m++)
#pragma unroll
                for (int r = 0; r < 4; r++) {
                    ps[m][r] += acc[m][n][r] * asv[n];
                    pd[m][r] += acc[m][n][r] * adv[n];
                }
#pragma unroll
        for (int off = 1; off < 16; off <<= 1)
#pragma unroll
            for (int m = 0; m < 4; m++)
#pragma unroll
                for (int r = 0; r < 4; r++) {
                    ps[m][r] += __shfl_xor(ps[m][r], off, 64);
                    pd[m][r] += __shfl_xor(pd[m][r], off, 64);
                }
        if (l16 == 0) {
#pragma unroll
            for (int m = 0; m < 4; m++)
#pragma unroll
                for (int r = 0; r < 4; r++) {
                    int row = bm + wr * 64 + m * 16 + quad * 4 + r;
                    if (row < M) {
                        as_n[row * 4 + head] = ps[m][r];
                        ad_n[row * 4 + head] = pd[m][r];
                    }
                }
        }
    }
}

// ---------------- 64x64 MFMA GEMM with fused attn (layer-3: N2=64, 1 head) ----------------
__global__ __launch_bounds__(256) void gemm64_mfma(const ushort_t* __restrict__ A,
                                                   const ushort_t* __restrict__ WT,
                                                   ushort_t* __restrict__ Cb,
                                                   const float* __restrict__ a_src,
                                                   const float* __restrict__ a_dst,
                                                   float* __restrict__ as_n,
                                                   float* __restrict__ ad_n,
                                                   int M, int K, int N2) {
    __shared__ ushort_t sA[64 * 32];  // 4 KB
    __shared__ ushort_t sB[64 * 32];  // 4 KB
    const int tid = threadIdx.x;
    const int wv = tid >> 6, lane = tid & 63;
    const int quad = lane >> 4, l16 = lane & 15;
    const int bm = blockIdx.x * 64;
    const int srow = tid >> 2, skof = (tid & 3) * 8;
    f32x4 acc[4] = {};

    int gm = bm + srow;
    gm = gm < M ? gm : M - 1;
    const ushort_t* pa = A + (size_t)gm * K + skof;
    const ushort_t* pb = WT + (size_t)srow * K + skof;

    for (int k0 = 0; k0 < K; k0 += 32) {
        *(float4*)(sA + srow * 32 + skof) = *(const float4*)(pa + k0);
        *(float4*)(sB + srow * 32 + skof) = *(const float4*)(pb + k0);
        __syncthreads();

        bf16x8 af = *(const bf16x8*)(sA + (wv * 16 + l16) * 32 + quad * 8);
#pragma unroll
        for (int j = 0; j < 4; j++) {
            bf16x8 bf = *(const bf16x8*)(sB + (j * 16 + l16) * 32 + quad * 8);
            acc[j] = __builtin_amdgcn_mfma_f32_16x16x32_bf16(af, bf, acc[j], 0, 0, 0);
        }
        __syncthreads();
    }

#pragma unroll
    for (int j = 0; j < 4; j++) {
        int col = j * 16 + l16;
#pragma unroll
        for (int r = 0; r < 4; r++) {
            int row = bm + wv * 16 + quad * 4 + r;
            if (row < M) Cb[(size_t)row * N2 + col] = f2b(acc[j][r]);
        }
    }

    // fused attn: the wave's 4 j-frags x 16 lanes span all 64 cols (single head)
    float asv[4], adv[4];
#pragma unroll
    for (int j = 0; j < 4; j++) {
        asv[j] = a_src[j * 16 + l16];
        adv[j] = a_dst[j * 16 + l16];
    }
    float ps[4] = {}, pd[4] = {};
#pragma unroll
    for (int j = 0; j < 4; j++)
#pragma unroll
        for (int r = 0; r < 4; r++) {
            ps[r] += acc[j][r] * asv[j];
            pd[r] += acc[j][r] * adv[j];
        }
#pragma unroll
    for (int off = 1; off < 16; off <<= 1)
#pragma unroll
        for (int r = 0; r < 4; r++) {
            ps[r] += __shfl_xor(ps[r], off, 64);
            pd[r] += __shfl_xor(pd[r], off, 64);
        }
    if (l16 == 0) {
#pragma unroll
        for (int r = 0; r < 4; r++) {
            int row = bm + wv * 16 + quad * 4 + r;
            if (row < M) {
                as_n[row] = ps[r];
                ad_n[row] = pd[r];
            }
        }
    }
}

// ---------------- XCD-sliced softmax aggregation v2 (CH=256) ----------------
// xs slice-major: xs[slice][N][32ch]; slice = blockIdx.x & 7 -> one XCD (round-robin),
// 3.2 MB/slice -> L2-resident. R8 loop shape restored: per dst, 4 lanes x 8ch (16B gathers),
// every lane walks ALL edges (den complete per-lane, NO cross-lane reduce),
// batched unroll-8 with clamp-and-zero => 8 gathers in flight per lane.
// Wave = 16 dsts; block = 64 dsts of one slice.
__global__ __launch_bounds__(256) void aggregate256_slice_kernel(
    const ushort_t* __restrict__ xs, const float* __restrict__ as_n,
    const float* __restrict__ ad_n, const int* __restrict__ rowoff,
    const int* __restrict__ ssrc, const float* __restrict__ bias,
    ushort_t* __restrict__ hout, int N) {
    const int bid = blockIdx.x;
    const int slice = bid & 7;
    const int db = bid >> 3;          // 64-dst block within slice
    const int tid = threadIdx.x;
    const int wv = tid >> 6, lane = tid & 63;
    const int grp = lane >> 2, sub = lane & 3;   // 16 dsts/wave, 4 ch-lanes/dst
    const int dd = db * 64 + wv * 16 + grp;
    if (dd >= N) return;
    const int h = slice >> 1;
    const int r0 = rowoff[dd], r1 = rowoff[dd + 1];
    const float adv = ad_n[dd * 4 + h];
    const uint4* xv = (const uint4*)xs;          // (slice*N + s)*4 + sub
    const size_t sbase = (size_t)slice * N;
    float a0 = 0, a1 = 0, a2 = 0, a3 = 0, a4 = 0, a5 = 0, a6 = 0, a7 = 0, den = 0;
    for (int i = r0; i < r1; i += 8) {
        int s[8];
        float g[8];
        uint4 u[8];
#pragma unroll
        for (int j = 0; j < 8; j++) {
            int t = i + j;
            s[j] = ssrc[t < r1 ? t : r0];
        }
#pragma unroll
        for (int j = 0; j < 8; j++) g[j] = as_n[s[j] * 4 + h];
#pragma unroll
        for (int j = 0; j < 8; j++) u[j] = xv[(sbase + s[j]) * 4 + sub];
#pragma unroll
        for (int j = 0; j < 8; j++) {
            float lg = g[j] + adv;
            lg = lg > 0.f ? lg : 0.2f * lg;
            float p = (i + j < r1) ? __expf(lg) : 0.f;
            den += p;
            a0 += p * lo16(u[j].x); a1 += p * hi16(u[j].x);
            a2 += p * lo16(u[j].y); a3 += p * hi16(u[j].y);
            a4 += p * lo16(u[j].z); a5 += p * hi16(u[j].z);
            a6 += p * lo16(u[j].w); a7 += p * hi16(u[j].w);
        }
    }
    float di = 1.f / (den + 1e-16f);
    const float4* bp = (const float4*)(bias + slice * 32 + sub * 8);
    float4 b0 = bp[0], b1 = bp[1];
    float v0 = a0 * di + b0.x, v1 = a1 * di + b0.y;
    float v2 = a2 * di + b0.z, v3 = a3 * di + b0.w;
    float v4 = a4 * di + b1.x, v5 = a5 * di + b1.y;
    float v6 = a6 * di + b1.z, v7 = a7 * di + b1.w;
    v0 = v0 > 0.f ? v0 : 0.f; v1 = v1 > 0.f ? v1 : 0.f;
    v2 = v2 > 0.f ? v2 : 0.f; v3 = v3 > 0.f ? v3 : 0.f;
    v4 = v4 > 0.f ? v4 : 0.f; v5 = v5 > 0.f ? v5 : 0.f;
    v6 = v6 > 0.f ? v6 : 0.f; v7 = v7 > 0.f ? v7 : 0.f;
    uint4 o;
    o.x = pack2(v0, v1); o.y = pack2(v2, v3);
    o.z = pack2(v4, v5); o.w = pack2(v6, v7);
    ((uint4*)hout)[(size_t)dd * 32 + slice * 4 + sub] = o;  // row-major [N][256] out
}

// ---------------- per-dst softmax-weighted aggregation (CH=64, layer 3) ----------------
__global__ __launch_bounds__(256) void aggregate64_kernel(const ushort_t* __restrict__ xl,
                                                          const float* __restrict__ as_n,
                                                          const float* __restrict__ ad_n,
                                                          const int* __restrict__ rowoff,
                                                          const int* __restrict__ ssrc,
                                                          const float* __restrict__ bias,
                                                          ushort_t* __restrict__ hout, int N) {
    const int tid = threadIdx.x;
    const int wv = tid >> 6, lane = tid & 63;
    const uint4* xv = (const uint4*)xl;
    const int grp = lane >> 3, l8 = lane & 7;
    const int dd = blockIdx.x * 32 + wv * 8 + grp;
    if (dd >= N) return;
    const int r0 = rowoff[dd], r1 = rowoff[dd + 1];
    const float adv = ad_n[dd];
    float a0 = 0, a1 = 0, a2 = 0, a3 = 0, a4 = 0, a5 = 0, a6 = 0, a7 = 0, den = 0;
    for (int i = r0; i < r1; i += 8) {
        int s[8];
        float g[8];
        uint4 u[8];
#pragma unroll
        for (int j = 0; j < 8; j++) {
            int t = i + j;
            s[j] = ssrc[t < r1 ? t : r0];
        }
#pragma unroll
        for (int j = 0; j < 8; j++) g[j] = as_n[s[j]];
#pragma unroll
        for (int j = 0; j < 8; j++) u[j] = xv[(size_t)s[j] * 8 + l8];
#pragma unroll
        for (int j = 0; j < 8; j++) {
            float lg = g[j] + adv;
            lg = lg > 0.f ? lg : 0.2f * lg;
            float p = (i + j < r1) ? __expf(lg) : 0.f;
            den += p;
            a0 += p * lo16(u[j].x); a1 += p * hi16(u[j].x);
            a2 += p * lo16(u[j].y); a3 += p * hi16(u[j].y);
            a4 += p * lo16(u[j].z); a5 += p * hi16(u[j].z);
            a6 += p * lo16(u[j].w); a7 += p * hi16(u[j].w);
        }
    }
    float di = 1.f / (den + 1e-16f);
    float4 b0 = ((const float4*)bias)[l8 * 2];
    float4 b1 = ((const float4*)bias)[l8 * 2 + 1];
    float v0 = a0 * di + b0.x, v1 = a1 * di + b0.y;
    float v2 = a2 * di + b0.z, v3 = a3 * di + b0.w;
    float v4 = a4 * di + b1.x, v5 = a5 * di + b1.y;
    float v6 = a6 * di + b1.z, v7 = a7 * di + b1.w;
    v0 = v0 > 0.f ? v0 : 0.f; v1 = v1 > 0.f ? v1 : 0.f;
    v2 = v2 > 0.f ? v2 : 0.f; v3 = v3 > 0.f ? v3 : 0.f;
    v4 = v4 > 0.f ? v4 : 0.f; v5 = v5 > 0.f ? v5 : 0.f;
    v6 = v6 > 0.f ? v6 : 0.f; v7 = v7 > 0.f ? v7 : 0.f;
    uint4 o;
    o.x = pack2(v0, v1); o.y = pack2(v2, v3);
    o.z = pack2(v4, v5); o.w = pack2(v6, v7);
    ((uint4*)hout)[(size_t)dd * 8 + l8] = o;
}

extern "C" void kernel_launch(void* const* d_in, const int* in_sizes, int n_in,
                              void* d_out, int out_size, void* d_ws, size_t ws_size,
                              hipStream_t stream) {
    const int N = in_sizes[0] / 128;  // 50000
    const int E = in_sizes[1] / 2;    // 800000
    const int Etot = E + N;

    const float* x = (const float*)d_in[0];  // fp32 input
    const int* ei = (const int*)d_in[1];
    const int* ei_src = ei;
    const int* ei_dst = ei + E;
    float* out = (float*)d_out;  // fp32 output

    const float* as1 = (const float*)d_in[3];
    const float* ad1 = (const float*)d_in[4];
    const float* b1  = (const float*)d_in[5];
    const float* as2 = (const float*)d_in[7];
    const float* ad2 = (const float*)d_in[8];
    const float* b2  = (const float*)d_in[9];
    const float* as3 = (const float*)d_in[11];
    const float* ad3 = (const float*)d_in[12];
    const float* b3  = (const float*)d_in[13];
    const float* bfc = (const float*)d_in[15];

    // ---- workspace layout (bf16 activations) ----
    ushort_t* bufX = (ushort_t*)d_ws;            // [N][256] bf16 (xl; slice-major)
    ushort_t* bufH = bufX + (size_t)N * 256;     // [N][256] bf16 (agg out)
    ushort_t* W1T  = bufH + (size_t)N * 256;     // 256x128 bf16
    ushort_t* W2T  = W1T + 32768;                // 256x256
    ushort_t* W3T  = W2T + 65536;                // 64x256
    ushort_t* WfcT = W3T + 16384;                // 512x64
    float* asn = (float*)(WfcT + 32768);         // N*4
    float* adn = asn + (size_t)N * 4;            // N*4
    int* deg    = (int*)(adn + (size_t)N * 4);   // N
    int* rowoff = deg + N;                       // N+1
    int* cursor = rowoff + N + 1;                // N
    int* ssrc   = cursor + N;                    // Etot
    int* bsum   = ssrc + Etot;                   // <=256
    int* boff   = bsum + 256;                    // <=256

    // weight transposes + deg zeroing in one launch
    transpose_all_kernel<<<576, 256, 0, stream>>>((const float*)d_in[2], (const float*)d_in[6],
                                                  (const float*)d_in[10], (const float*)d_in[14],
                                                  W1T, W2T, W3T, WfcT, deg, N);

    // CSR build
    int eb = (Etot + 255) / 256;
    degree_kernel<<<eb, 256, 0, stream>>>(ei_dst, deg, E, Etot);
    const int NBLK = (N + 255) / 256;  // 196 (<= 256)
    partial_sum_kernel<<<NBLK, 256, 0, stream>>>(deg, bsum, N);
    scan_bsum_kernel<<<1, 256, 0, stream>>>(bsum, boff, rowoff, NBLK, N);
    block_scan_kernel<<<NBLK, 256, 0, stream>>>(deg, boff, rowoff, cursor, N);
    scatter_kernel<<<eb, 256, 0, stream>>>(ei_src, ei_dst, cursor, ssrc, E, Etot);

    const int MB128 = (N + 127) / 128;  // 391
    const int MB64 = (N + 63) / 64;     // 782
    const int nbS = ((N + 63) / 64) * 8;  // 6256 blocks (8 slices x 782)
    int nb32 = (N + 31) / 32;

    // layer 1: x(fp32) @ W1 -> bufX(slice-major bf16) + fused attn; sliced aggregate -> bufH
    gemm128_mfma<float, 2, true><<<dim3(MB128, 2), 256, 0, stream>>>(
        x, W1T, nullptr, bufX, nullptr, as1, ad1, asn, adn, N, 128, 256);
    aggregate256_slice_kernel<<<nbS, 256, 0, stream>>>(bufX, asn, adn, rowoff, ssrc, b1, bufH, N);

    // layer 2
    gemm128_mfma<ushort_t, 2, true><<<dim3(MB128, 2), 256, 0, stream>>>(
        bufH, W2T, nullptr, bufX, nullptr, as2, ad2, asn, adn, N, 256, 256);
    aggregate256_slice_kernel<<<nbS, 256, 0, stream>>>(bufX, asn, adn, rowoff, ssrc, b2, bufH, N);

    // layer 3 (H=1, C=64) + fused attn (normal layout)
    gemm64_mfma<<<dim3(MB64, 1), 256, 0, stream>>>(bufH, W3T, bufX, as3, ad3, asn, adn, N, 256, 64);
    aggregate64_kernel<<<nb32, 256, 0, stream>>>(bufX, asn, adn, rowoff, ssrc, b3, bufH, N);

    // final fc: relu(bufH[N,64] @ Wfc + bfc) -> fp32 out
    gemm128_mfma<ushort_t, 1, false><<<dim3(MB128, 4), 256, 0, stream>>>(
        bufH, WfcT, out, nullptr, bfc, nullptr, nullptr, nullptr, nullptr, N, 64, 512);
}

// Round 11
// 478.117 us; speedup vs baseline: 1.1317x; 1.0800x over previous
//
#include <hip/hip_runtime.h>
#include <cstdint>
#include <cstddef>

typedef unsigned short ushort_t;
typedef __bf16 bf16x8 __attribute__((ext_vector_type(8)));
typedef float f32x4 __attribute__((ext_vector_type(4)));

__device__ __forceinline__ float b2f(ushort_t u) {
    return __uint_as_float(((unsigned int)u) << 16);
}
__device__ __forceinline__ ushort_t f2b(float f) {
    __bf16 h = (__bf16)f;  // RNE
    return *(ushort_t*)&h;
}
// bf16 pair unpack from packed uint (little-endian: lo ushort = even channel)
__device__ __forceinline__ float lo16(unsigned int u) { return __uint_as_float(u << 16); }
__device__ __forceinline__ float hi16(unsigned int u) { return __uint_as_float(u & 0xffff0000u); }
__device__ __forceinline__ unsigned int pack2(float a, float b) {
    return ((unsigned int)f2b(b) << 16) | (unsigned int)f2b(a);
}

// stage 8 contiguous elements into LDS as bf16 (overloaded on source type)
__device__ __forceinline__ void stage8(const float* __restrict__ g, ushort_t* s) {
    float4 f0 = *(const float4*)g;
    float4 f1 = *(const float4*)(g + 4);
    union { ushort_t u[8]; uint4 v; } t;
    t.u[0] = f2b(f0.x); t.u[1] = f2b(f0.y); t.u[2] = f2b(f0.z); t.u[3] = f2b(f0.w);
    t.u[4] = f2b(f1.x); t.u[5] = f2b(f1.y); t.u[6] = f2b(f1.z); t.u[7] = f2b(f1.w);
    *(uint4*)s = t.v;
}
__device__ __forceinline__ void stage8(const ushort_t* __restrict__ g, ushort_t* s) {
    *(float4*)s = *(const float4*)g;  // already bf16: raw 16B copy
}

// ---------------- all 4 weight transposes + deg zeroing in one launch ----------------
__device__ __forceinline__ void tr_seg(int id, const float* __restrict__ W,
                                       ushort_t* __restrict__ WT, int K, int N2) {
    int n = id / K, k = id - n * K;
    WT[id] = f2b(W[k * N2 + n]);
}
__global__ __launch_bounds__(256) void transpose_all_kernel(const float* __restrict__ W1,
                                                            const float* __restrict__ W2,
                                                            const float* __restrict__ W3,
                                                            const float* __restrict__ Wfc,
                                                            ushort_t* __restrict__ W1T,
                                                            ushort_t* __restrict__ W2T,
                                                            ushort_t* __restrict__ W3T,
                                                            ushort_t* __restrict__ WfcT,
                                                            int* __restrict__ deg, int n) {
    int id = blockIdx.x * 256 + threadIdx.x;
    if (id < n) deg[id] = 0;  // fused memset (runs before degree_kernel in-stream)
    if (id < 32768) { tr_seg(id, W1, W1T, 128, 256); return; }
    id -= 32768;
    if (id < 65536) { tr_seg(id, W2, W2T, 256, 256); return; }
    id -= 65536;
    if (id < 16384) { tr_seg(id, W3, W3T, 256, 64); return; }
    id -= 16384;
    if (id < 32768) { tr_seg(id, Wfc, WfcT, 64, 512); return; }
}

// ---------------- CSR build ----------------
__global__ __launch_bounds__(256) void degree_kernel(const int* __restrict__ ei_dst,
                                                     int* __restrict__ deg, int E, int Etot) {
    int e = blockIdx.x * 256 + threadIdx.x;
    if (e >= Etot) return;
    int d = (e < E) ? ei_dst[e] : (e - E);
    atomicAdd(&deg[d], 1);
}

__global__ __launch_bounds__(256) void partial_sum_kernel(const int* __restrict__ deg,
                                                          int* __restrict__ bsum, int n) {
    __shared__ int ws[4];
    int t = threadIdx.x;
    int i = blockIdx.x * 256 + t;
    int v = (i < n) ? deg[i] : 0;
#pragma unroll
    for (int off = 32; off; off >>= 1) v += __shfl_xor(v, off, 64);
    if ((t & 63) == 0) ws[t >> 6] = v;
    __syncthreads();
    if (t == 0) bsum[blockIdx.x] = ws[0] + ws[1] + ws[2] + ws[3];
}

__global__ __launch_bounds__(256) void scan_bsum_kernel(const int* __restrict__ bsum,
                                                        int* __restrict__ boff,
                                                        int* __restrict__ rowoff,
                                                        int nblk, int n) {
    __shared__ int sm[256];
    int t = threadIdx.x;
    int v = (t < nblk) ? bsum[t] : 0;
    sm[t] = v;
    __syncthreads();
#pragma unroll
    for (int off = 1; off < 256; off <<= 1) {
        int u = (t >= off) ? sm[t - off] : 0;
        __syncthreads();
        sm[t] += u;
        __syncthreads();
    }
    if (t < nblk) boff[t] = sm[t] - v;
    if (t == 255) rowoff[n] = sm[255];
}

// per-block inclusive scan + block offset -> exclusive rowoff[i]; also cursor[i]=rowoff[i]
__global__ __launch_bounds__(256) void block_scan_kernel(const int* __restrict__ deg,
                                                         const int* __restrict__ boff,
                                                         int* __restrict__ rowoff,
                                                         int* __restrict__ cursor, int n) {
    __shared__ int sm[256];
    int t = threadIdx.x;
    int i = blockIdx.x * 256 + t;
    int v = (i < n) ? deg[i] : 0;
    sm[t] = v;
    __syncthreads();
#pragma unroll
    for (int off = 1; off < 256; off <<= 1) {
        int u = (t >= off) ? sm[t - off] : 0;
        __syncthreads();
        sm[t] += u;
        __syncthreads();
    }
    if (i < n) {
        int r = boff[blockIdx.x] + sm[t] - v;
        rowoff[i] = r;
        cursor[i] = r;
    }
}

__global__ __launch_bounds__(256) void scatter_kernel(const int* __restrict__ ei_src,
                                                      const int* __restrict__ ei_dst,
                                                      int* __restrict__ cursor,
                                                      int* __restrict__ ssrc, int E, int Etot) {
    int e = blockIdx.x * 256 + threadIdx.x;
    if (e >= Etot) return;
    int s, d;
    if (e < E) { s = ei_src[e]; d = ei_dst[e]; } else { s = d = e - E; }
    int pos = atomicAdd(&cursor[d], 1);
    ssrc[pos] = s;
}

// ---------------- 128x128 MFMA GEMM, optional fused attention epilogue ----------------
// 256 thr = 4 waves in 2x2; wave (wr,wc) owns 64x64 quadrant; 4x4 16x16-frag accum.
// EPI: 1 = fp32 bias+relu out (nontemporal store: out is never re-read on device),
//      2 = bf16 out + fused attn (wave holds all 64 ch of one head per row).
template <typename TA, int EPI>
__global__ __launch_bounds__(256) void gemm128_mfma(const TA* __restrict__ A,
                                                    const ushort_t* __restrict__ WT,
                                                    float* __restrict__ C,
                                                    ushort_t* __restrict__ Cb,
                                                    const float* __restrict__ bias,
                                                    const float* __restrict__ a_src,
                                                    const float* __restrict__ a_dst,
                                                    float* __restrict__ as_n,
                                                    float* __restrict__ ad_n,
                                                    int M, int K, int N2) {
    __shared__ ushort_t sA[128 * 32];  // 8 KB
    __shared__ ushort_t sB[128 * 32];  // 8 KB
    const int tid = threadIdx.x;
    const int wv = tid >> 6, lane = tid & 63;
    const int wr = wv >> 1, wc = wv & 1;
    const int quad = lane >> 4, l16 = lane & 15;
    const int bm = blockIdx.x * 128, bn = blockIdx.y * 128;
    const int sr0 = tid >> 2, sc = (tid & 3) * 8;
    const int sr1 = sr0 + 64;
    f32x4 acc[4][4] = {};

    int ga0 = bm + sr0; ga0 = ga0 < M ? ga0 : M - 1;  // clamp tail (dup read; masked store)
    int ga1 = bm + sr1; ga1 = ga1 < M ? ga1 : M - 1;
    const TA* pa0 = A + (size_t)ga0 * K + sc;
    const TA* pa1 = A + (size_t)ga1 * K + sc;
    const ushort_t* pb0 = WT + (size_t)(bn + sr0) * K + sc;
    const ushort_t* pb1 = WT + (size_t)(bn + sr1) * K + sc;

    for (int k0 = 0; k0 < K; k0 += 32) {
        stage8(pa0 + k0, sA + sr0 * 32 + sc);
        stage8(pa1 + k0, sA + sr1 * 32 + sc);
        stage8(pb0 + k0, sB + sr0 * 32 + sc);
        stage8(pb1 + k0, sB + sr1 * 32 + sc);
        __syncthreads();

        bf16x8 af[4], bfr[4];
#pragma unroll
        for (int m = 0; m < 4; m++)
            af[m] = *(const bf16x8*)(sA + (wr * 64 + m * 16 + l16) * 32 + quad * 8);
#pragma unroll
        for (int n = 0; n < 4; n++)
            bfr[n] = *(const bf16x8*)(sB + (wc * 64 + n * 16 + l16) * 32 + quad * 8);
#pragma unroll
        for (int m = 0; m < 4; m++)
#pragma unroll
            for (int n = 0; n < 4; n++)
                acc[m][n] = __builtin_amdgcn_mfma_f32_16x16x32_bf16(af[m], bfr[n], acc[m][n], 0, 0, 0);
        __syncthreads();
    }

#pragma unroll
    for (int n = 0; n < 4; n++) {
        int col = bn + wc * 64 + n * 16 + l16;
        float bv = (EPI == 1) ? bias[col] : 0.f;
#pragma unroll
        for (int m = 0; m < 4; m++) {
#pragma unroll
            for (int r = 0; r < 4; r++) {
                int row = bm + wr * 64 + m * 16 + quad * 4 + r;
                if (row < M) {
                    float v = acc[m][n][r];
                    if (EPI == 1) {
                        v += bv;
                        v = v > 0.f ? v : 0.f;
                        __builtin_nontemporal_store(v, &C[(size_t)row * N2 + col]);
                    } else {
                        Cb[(size_t)row * N2 + col] = f2b(v);
                    }
                }
            }
        }
    }

    if (EPI == 2) {
        const int head = blockIdx.y * 2 + wc;
        float asv[4], adv[4];
#pragma unroll
        for (int n = 0; n < 4; n++) {
            asv[n] = a_src[head * 64 + n * 16 + l16];
            adv[n] = a_dst[head * 64 + n * 16 + l16];
        }
        float ps[4][4] = {}, pd[4][4] = {};
#pragma unroll
        for (int n = 0; n < 4; n++)
#pragma unroll
            for (int m = 0; m < 4; m++)
#pragma unroll
                for (int r = 0; r < 4; r++) {
                    ps[m][r] += acc[m][n][r] * asv[n];
                    pd[m][r] += acc[m][n][r] * adv[n];
                }
#pragma unroll
        for (int off = 1; off < 16; off <<= 1)
#pragma unroll
            for (int m = 0; m < 4; m++)
#pragma unroll
                for (int r = 0; r < 4; r++) {
                    ps[m][r] += __shfl_xor(ps[m][r], off, 64);
                    pd[m][r] += __shfl_xor(pd[m][r], off, 64);
                }
        if (l16 == 0) {
#pragma unroll
            for (int m = 0; m < 4; m++)
#pragma unroll
                for (int r = 0; r < 4; r++) {
                    int row = bm + wr * 64 + m * 16 + quad * 4 + r;
                    if (row < M) {
                        as_n[row * 4 + head] = ps[m][r];
                        ad_n[row * 4 + head] = pd[m][r];
                    }
                }
        }
    }
}

// ---------------- 64x64 MFMA GEMM with fused attn (layer-3: N2=64, 1 head) ----------------
__global__ __launch_bounds__(256) void gemm64_mfma(const ushort_t* __restrict__ A,
                                                   const ushort_t* __restrict__ WT,
                                                   ushort_t* __restrict__ Cb,
                                                   const float* __restrict__ a_src,
                                                   const float* __restrict__ a_dst,
                                                   float* __restrict__ as_n,
                                                   float* __restrict__ ad_n,
                                                   int M, int K, int N2) {
    __shared__ ushort_t sA[64 * 32];  // 4 KB
    __shared__ ushort_t sB[64 * 32];  // 4 KB
    const int tid = threadIdx.x;
    const int wv = tid >> 6, lane = tid & 63;
    const int quad = lane >> 4, l16 = lane & 15;
    const int bm = blockIdx.x * 64;
    const int srow = tid >> 2, skof = (tid & 3) * 8;
    f32x4 acc[4] = {};

    int gm = bm + srow;
    gm = gm < M ? gm : M - 1;
    const ushort_t* pa = A + (size_t)gm * K + skof;
    const ushort_t* pb = WT + (size_t)srow * K + skof;

    for (int k0 = 0; k0 < K; k0 += 32) {
        *(float4*)(sA + srow * 32 + skof) = *(const float4*)(pa + k0);
        *(float4*)(sB + srow * 32 + skof) = *(const float4*)(pb + k0);
        __syncthreads();

        bf16x8 af = *(const bf16x8*)(sA + (wv * 16 + l16) * 32 + quad * 8);
#pragma unroll
        for (int j = 0; j < 4; j++) {
            bf16x8 bf = *(const bf16x8*)(sB + (j * 16 + l16) * 32 + quad * 8);
            acc[j] = __builtin_amdgcn_mfma_f32_16x16x32_bf16(af, bf, acc[j], 0, 0, 0);
        }
        __syncthreads();
    }

#pragma unroll
    for (int j = 0; j < 4; j++) {
        int col = j * 16 + l16;
#pragma unroll
        for (int r = 0; r < 4; r++) {
            int row = bm + wv * 16 + quad * 4 + r;
            if (row < M) Cb[(size_t)row * N2 + col] = f2b(acc[j][r]);
        }
    }

    // fused attn: the wave's 4 j-frags x 16 lanes span all 64 cols (single head)
    float asv[4], adv[4];
#pragma unroll
    for (int j = 0; j < 4; j++) {
        asv[j] = a_src[j * 16 + l16];
        adv[j] = a_dst[j * 16 + l16];
    }
    float ps[4] = {}, pd[4] = {};
#pragma unroll
    for (int j = 0; j < 4; j++)
#pragma unroll
        for (int r = 0; r < 4; r++) {
            ps[r] += acc[j][r] * asv[j];
            pd[r] += acc[j][r] * adv[j];
        }
#pragma unroll
    for (int off = 1; off < 16; off <<= 1)
#pragma unroll
        for (int r = 0; r < 4; r++) {
            ps[r] += __shfl_xor(ps[r], off, 64);
            pd[r] += __shfl_xor(pd[r], off, 64);
        }
    if (l16 == 0) {
#pragma unroll
        for (int r = 0; r < 4; r++) {
            int row = bm + wv * 16 + quad * 4 + r;
            if (row < M) {
                as_n[row] = ps[r];
                ad_n[row] = pd[r];
            }
        }
    }
}

// ---------------- per-dst softmax-weighted aggregation (R8 structure) ----------------
// CH=256: 32 lanes/dst (lane=8ch dwordx4), 2 dst/wave. CH=64: 8 lanes/dst, 8 dst/wave.
// Clamp-and-zero padding: OOB slots clamp to r0 (L1-hit dup), p=0 kills contribution.
template <int CH>
__global__ __launch_bounds__(256) void aggregate_kernel(const ushort_t* __restrict__ xl,
                                                        const float* __restrict__ as_n,
                                                        const float* __restrict__ ad_n,
                                                        const int* __restrict__ rowoff,
                                                        const int* __restrict__ ssrc,
                                                        const float* __restrict__ bias,
                                                        ushort_t* __restrict__ hout, int N) {
    const int tid = threadIdx.x;
    const int wv = tid >> 6, lane = tid & 63;
    const uint4* xv = (const uint4*)xl;
    if (CH == 256) {
        const int hw = lane >> 5, l32 = lane & 31;
        const int dd = blockIdx.x * 8 + wv * 2 + hw;
        if (dd >= N) return;
        const int h = l32 >> 3;
        const int r0 = rowoff[dd], r1 = rowoff[dd + 1];
        const float adv = ad_n[dd * 4 + h];
        float a0 = 0, a1 = 0, a2 = 0, a3 = 0, a4 = 0, a5 = 0, a6 = 0, a7 = 0, den = 0;
        for (int i = r0; i < r1; i += 8) {
            int s[8];
            float g[8];
            uint4 u[8];
#pragma unroll
            for (int j = 0; j < 8; j++) {
                int t = i + j;
                s[j] = ssrc[t < r1 ? t : r0];
            }
#pragma unroll
            for (int j = 0; j < 8; j++) g[j] = as_n[s[j] * 4 + h];
#pragma unroll
            for (int j = 0; j < 8; j++) u[j] = xv[(size_t)s[j] * 32 + l32];
#pragma unroll
            for (int j = 0; j < 8; j++) {
                float lg = g[j] + adv;
                lg = lg > 0.f ? lg : 0.2f * lg;
                float p = (i + j < r1) ? __expf(lg) : 0.f;
                den += p;
                a0 += p * lo16(u[j].x); a1 += p * hi16(u[j].x);
                a2 += p * lo16(u[j].y); a3 += p * hi16(u[j].y);
                a4 += p * lo16(u[j].z); a5 += p * hi16(u[j].z);
                a6 += p * lo16(u[j].w); a7 += p * hi16(u[j].w);
            }
        }
        float di = 1.f / (den + 1e-16f);
        float4 b0 = ((const float4*)bias)[l32 * 2];
        float4 b1 = ((const float4*)bias)[l32 * 2 + 1];
        float v0 = a0 * di + b0.x, v1 = a1 * di + b0.y;
        float v2 = a2 * di + b0.z, v3 = a3 * di + b0.w;
        float v4 = a4 * di + b1.x, v5 = a5 * di + b1.y;
        float v6 = a6 * di + b1.z, v7 = a7 * di + b1.w;
        v0 = v0 > 0.f ? v0 : 0.f; v1 = v1 > 0.f ? v1 : 0.f;
        v2 = v2 > 0.f ? v2 : 0.f; v3 = v3 > 0.f ? v3 : 0.f;
        v4 = v4 > 0.f ? v4 : 0.f; v5 = v5 > 0.f ? v5 : 0.f;
        v6 = v6 > 0.f ? v6 : 0.f; v7 = v7 > 0.f ? v7 : 0.f;
        uint4 o;
        o.x = pack2(v0, v1); o.y = pack2(v2, v3);
        o.z = pack2(v4, v5); o.w = pack2(v6, v7);
        ((uint4*)hout)[(size_t)dd * 32 + l32] = o;
    } else {
        const int grp = lane >> 3, l8 = lane & 7;
        const int dd = blockIdx.x * 32 + wv * 8 + grp;
        if (dd >= N) return;
        const int r0 = rowoff[dd], r1 = rowoff[dd + 1];
        const float adv = ad_n[dd];
        float a0 = 0, a1 = 0, a2 = 0, a3 = 0, a4 = 0, a5 = 0, a6 = 0, a7 = 0, den = 0;
        for (int i = r0; i < r1; i += 8) {
            int s[8];
            float g[8];
            uint4 u[8];
#pragma unroll
            for (int j = 0; j < 8; j++) {
                int t = i + j;
                s[j] = ssrc[t < r1 ? t : r0];
            }
#pragma unroll
            for (int j = 0; j < 8; j++) g[j] = as_n[s[j]];
#pragma unroll
            for (int j = 0; j < 8; j++) u[j] = xv[(size_t)s[j] * 8 + l8];
#pragma unroll
            for (int j = 0; j < 8; j++) {
                float lg = g[j] + adv;
                lg = lg > 0.f ? lg : 0.2f * lg;
                float p = (i + j < r1) ? __expf(lg) : 0.f;
                den += p;
                a0 += p * lo16(u[j].x); a1 += p * hi16(u[j].x);
                a2 += p * lo16(u[j].y); a3 += p * hi16(u[j].y);
                a4 += p * lo16(u[j].z); a5 += p * hi16(u[j].z);
                a6 += p * lo16(u[j].w); a7 += p * hi16(u[j].w);
            }
        }
        float di = 1.f / (den + 1e-16f);
        float4 b0 = ((const float4*)bias)[l8 * 2];
        float4 b1 = ((const float4*)bias)[l8 * 2 + 1];
        float v0 = a0 * di + b0.x, v1 = a1 * di + b0.y;
        float v2 = a2 * di + b0.z, v3 = a3 * di + b0.w;
        float v4 = a4 * di + b1.x, v5 = a5 * di + b1.y;
        float v6 = a6 * di + b1.z, v7 = a7 * di + b1.w;
        v0 = v0 > 0.f ? v0 : 0.f; v1 = v1 > 0.f ? v1 : 0.f;
        v2 = v2 > 0.f ? v2 : 0.f; v3 = v3 > 0.f ? v3 : 0.f;
        v4 = v4 > 0.f ? v4 : 0.f; v5 = v5 > 0.f ? v5 : 0.f;
        v6 = v6 > 0.f ? v6 : 0.f; v7 = v7 > 0.f ? v7 : 0.f;
        uint4 o;
        o.x = pack2(v0, v1); o.y = pack2(v2, v3);
        o.z = pack2(v4, v5); o.w = pack2(v6, v7);
        ((uint4*)hout)[(size_t)dd * 8 + l8] = o;
    }
}

extern "C" void kernel_launch(void* const* d_in, const int* in_sizes, int n_in,
                              void* d_out, int out_size, void* d_ws, size_t ws_size,
                              hipStream_t stream) {
    const int N = in_sizes[0] / 128;  // 50000
    const int E = in_sizes[1] / 2;    // 800000
    const int Etot = E + N;

    const float* x = (const float*)d_in[0];  // fp32 input
    const int* ei = (const int*)d_in[1];
    const int* ei_src = ei;
    const int* ei_dst = ei + E;
    float* out = (float*)d_out;  // fp32 output

    const float* as1 = (const float*)d_in[3];
    const float* ad1 = (const float*)d_in[4];
    const float* b1  = (const float*)d_in[5];
    const float* as2 = (const float*)d_in[7];
    const float* ad2 = (const float*)d_in[8];
    const float* b2  = (const float*)d_in[9];
    const float* as3 = (const float*)d_in[11];
    const float* ad3 = (const float*)d_in[12];
    const float* b3  = (const float*)d_in[13];
    const float* bfc = (const float*)d_in[15];

    // ---- workspace layout (bf16 activations) ----
    ushort_t* bufX = (ushort_t*)d_ws;            // [N][256] bf16 (xl, GEMM out)
    ushort_t* bufH = bufX + (size_t)N * 256;     // [N][256] bf16 (agg out)
    ushort_t* W1T  = bufH + (size_t)N * 256;     // 256x128 bf16
    ushort_t* W2T  = W1T + 32768;                // 256x256
    ushort_t* W3T  = W2T + 65536;                // 64x256
    ushort_t* WfcT = W3T + 16384;                // 512x64
    float* asn = (float*)(WfcT + 32768);         // N*4
    float* adn = asn + (size_t)N * 4;            // N*4
    int* deg    = (int*)(adn + (size_t)N * 4);   // N
    int* rowoff = deg + N;                       // N+1
    int* cursor = rowoff + N + 1;                // N
    int* ssrc   = cursor + N;                    // Etot
    int* bsum   = ssrc + Etot;                   // <=256
    int* boff   = bsum + 256;                    // <=256

    // weight transposes + deg zeroing in one launch
    transpose_all_kernel<<<576, 256, 0, stream>>>((const float*)d_in[2], (const float*)d_in[6],
                                                  (const float*)d_in[10], (const float*)d_in[14],
                                                  W1T, W2T, W3T, WfcT, deg, N);

    // CSR build
    int eb = (Etot + 255) / 256;
    degree_kernel<<<eb, 256, 0, stream>>>(ei_dst, deg, E, Etot);
    const int NBLK = (N + 255) / 256;  // 196 (<= 256)
    partial_sum_kernel<<<NBLK, 256, 0, stream>>>(deg, bsum, N);
    scan_bsum_kernel<<<1, 256, 0, stream>>>(bsum, boff, rowoff, NBLK, N);
    block_scan_kernel<<<NBLK, 256, 0, stream>>>(deg, boff, rowoff, cursor, N);
    scatter_kernel<<<eb, 256, 0, stream>>>(ei_src, ei_dst, cursor, ssrc, E, Etot);

    const int MB128 = (N + 127) / 128;  // 391
    const int MB64 = (N + 63) / 64;     // 782
    int nb8 = (N + 7) / 8;
    int nb32 = (N + 31) / 32;

    // layer 1: x(fp32) @ W1 -> bufX(bf16) + fused attn; aggregate -> bufH(bf16)
    gemm128_mfma<float, 2><<<dim3(MB128, 2), 256, 0, stream>>>(
        x, W1T, nullptr, bufX, nullptr, as1, ad1, asn, adn, N, 128, 256);
    aggregate_kernel<256><<<nb8, 256, 0, stream>>>(bufX, asn, adn, rowoff, ssrc, b1, bufH, N);

    // layer 2
    gemm128_mfma<ushort_t, 2><<<dim3(MB128, 2), 256, 0, stream>>>(
        bufH, W2T, nullptr, bufX, nullptr, as2, ad2, asn, adn, N, 256, 256);
    aggregate_kernel<256><<<nb8, 256, 0, stream>>>(bufX, asn, adn, rowoff, ssrc, b2, bufH, N);

    // layer 3 (H=1, C=64) + fused attn
    gemm64_mfma<<<dim3(MB64, 1), 256, 0, stream>>>(bufH, W3T, bufX, as3, ad3, asn, adn, N, 256, 64);
    aggregate_kernel<64><<<nb32, 256, 0, stream>>>(bufX, asn, adn, rowoff, ssrc, b3, bufH, N);

    // final fc: relu(bufH[N,64] @ Wfc + bfc) -> fp32 out (nontemporal store)
    gemm128_mfma<ushort_t, 1><<<dim3(MB128, 4), 256, 0, stream>>>(
        bufH, WfcT, out, nullptr, bfc, nullptr, nullptr, nullptr, nullptr, N, 64, 512);
}